// Round 12
// baseline (128.826 us; speedup 1.0000x reference)
//
#include <hip/hip_runtime.h>
#include <stdint.h>
#include <stddef.h>

#define NTOK 4096
#define DDIM 1024

typedef __attribute__((ext_vector_type(4))) float f32x4;
typedef __attribute__((ext_vector_type(8))) short s16x8;
typedef __attribute__((ext_vector_type(4))) unsigned short u16x4;
typedef __attribute__((ext_vector_type(4))) int i32x4;

__device__ __forceinline__ unsigned short f2bf(float f) {
  union { float f; unsigned u; } v; v.f = f;
  unsigned u = v.u + 0x7fffu + ((v.u >> 16) & 1u);
  return (unsigned short)(u >> 16);
}

__device__ __forceinline__ void gload_lds16(const void* g, void* l) {
  __builtin_amdgcn_global_load_lds(
      (const __attribute__((address_space(1))) void*)g,
      (__attribute__((address_space(3))) void*)l, 16, 0, 0);
}

#define VMWAIT(N) asm volatile("s_waitcnt vmcnt(" #N ")" ::: "memory")

// ---------- fused fp32->bf16 convert + lin dot, both inputs in one launch ----------
__global__ void convlin2_k(const float* __restrict__ xl, const float* __restrict__ xr,
                           const float* __restrict__ wl, const float* __restrict__ wr,
                           const float* __restrict__ bl, const float* __restrict__ br,
                           const float* __restrict__ bias,
                           unsigned short* __restrict__ xlb, unsigned short* __restrict__ xrb,
                           float* __restrict__ linl, float* __restrict__ linr) {
  const int isR = blockIdx.x >> 10;
  const float* x = isR ? xr : xl;
  const float* w = isR ? wr : wl;
  const float badd = isR ? br[0] : (bl[0] + bias[0]);
  unsigned short* xb = isR ? xrb : xlb;
  float* lin = isR ? linr : linl;

  int wv = threadIdx.x >> 6, lane = threadIdx.x & 63;
  int row = ((blockIdx.x & 1023) << 2) + wv;
  const f32x4* xrow = (const f32x4*)(x + (size_t)row * DDIM);
  const f32x4* w4 = (const f32x4*)w;
  u16x4* xb4 = (u16x4*)(xb + (size_t)row * DDIM);
  float s = 0.f;
  for (int j = lane; j < DDIM / 4; j += 64) {
    f32x4 a = xrow[j], c = w4[j];
    s += a[0] * c[0] + a[1] * c[1] + a[2] * c[2] + a[3] * c[3];
    u16x4 o;
    o[0] = f2bf(a[0]); o[1] = f2bf(a[1]); o[2] = f2bf(a[2]); o[3] = f2bf(a[3]);
    xb4[j] = o;
  }
#pragma unroll
  for (int off = 32; off; off >>= 1) s += __shfl_down(s, off);
  if (lane == 0) lin[row] = s + badd;
}

// ---------- transpose-convert M fp32 -> Mt bf16 ----------
__global__ void transpose_bf16_k(const float* __restrict__ M,
                                 unsigned short* __restrict__ Mt) {
  __shared__ unsigned short tile[32][33];
  int tx = threadIdx.x, ty = threadIdx.y;
  int bx = blockIdx.x, by = blockIdx.y;
  int x = bx * 32 + tx;
  for (int i = ty; i < 32; i += 8)
    tile[i][tx] = f2bf(M[(size_t)(by * 32 + i) * DDIM + x]);
  __syncthreads();
  int ox = by * 32 + tx;
  for (int i = ty; i < 32; i += 8)
    Mt[(size_t)(bx * 32 + i) * DDIM + ox] = tile[tx][i];
}

// ---------- detect mask element width ----------
__global__ void detect_mask_k(const unsigned char* __restrict__ m, int* __restrict__ flag) {
  __shared__ int f;
  if (threadIdx.x == 0) f = 0;
  __syncthreads();
  int any = 0;
  for (int i = threadIdx.x; i < 4096; i += 256)
    if ((i & 3) && m[i]) any = 1;
  if (any) atomicOr(&f, 1);
  __syncthreads();
  if (threadIdx.x == 0) *flag = f;  // 1 => byte mask, 0 => int32 mask
}

// ---------- GEMM1: double-buffered 64x128 BT GEMM (unchanged, passing) ----------
__launch_bounds__(512, 4)
__global__ void gemm1_k(const unsigned short* __restrict__ A,
                        const unsigned short* __restrict__ B,
                        unsigned short* __restrict__ Cb) {
  constexpr int BM = 64, BN = 128, K = DDIM;
  constexpr int MF = 2, NF = 2, AI = 1, BI = 2;
  __shared__ unsigned short As[2][BM][64];
  __shared__ unsigned short Bs[2][BN][64];

  const int lin = blockIdx.x;
  const int cpx = gridDim.x >> 3;
  const int swz = (lin & 7) * cpx + (lin >> 3);
  const int bi = swz >> 3, bj = swz & 7;

  const int tid = threadIdx.x;
  const int wid = tid >> 6, lane = tid & 63;
  const int wr2 = wid >> 2, wc2 = wid & 3;
  const int l15 = lane & 15, l16 = lane >> 4;
  const int xm = lane & 7;

  const int srow0 = tid >> 3;
  const int swslot = (tid & 7) ^ (srow0 & 7);
  const unsigned short* Ag = A + (size_t)(bi * BM + srow0) * K + swslot * 8;
  const unsigned short* Bg = B + (size_t)(bj * BN + srow0) * K + swslot * 8;

  f32x4 acc[MF][NF] = {};

#define STAGE_G1(BUF, K0)                                                    \
  {                                                                          \
    _Pragma("unroll") for (int j = 0; j < AI; ++j)                           \
        gload_lds16(Ag + (size_t)(j * 64) * K + (K0),                        \
                    &As[BUF][0][0] + j * 4096 + wid * 512);                  \
    _Pragma("unroll") for (int j = 0; j < BI; ++j)                           \
        gload_lds16(Bg + (size_t)(j * 64) * K + (K0),                        \
                    &Bs[BUF][0][0] + j * 4096 + wid * 512);                  \
  }

  STAGE_G1(0, 0)
  VMWAIT(0);
  __builtin_amdgcn_s_barrier();

  for (int t = 0; t < 16; ++t) {
    const int cur = t & 1, nxt = cur ^ 1;
    if (t < 15) STAGE_G1(nxt, (t + 1) * 64)
#pragma unroll
    for (int kk = 0; kk < 2; ++kk) {
      s16x8 Areg[MF], Breg[NF];
#pragma unroll
      for (int m = 0; m < MF; ++m)
        Areg[m] = *(const s16x8*)&As[cur][wr2 * 32 + m * 16 + l15]
                                     [(((kk << 2) | l16) ^ xm) << 3];
#pragma unroll
      for (int n = 0; n < NF; ++n)
        Breg[n] = *(const s16x8*)&Bs[cur][wc2 * 32 + n * 16 + l15]
                                     [(((kk << 2) | l16) ^ xm) << 3];
      __builtin_amdgcn_s_setprio(1);
#pragma unroll
      for (int m = 0; m < MF; ++m)
#pragma unroll
        for (int n = 0; n < NF; ++n)
          acc[m][n] = __builtin_amdgcn_mfma_f32_16x16x32_bf16(
              Areg[m], Breg[n], acc[m][n], 0, 0, 0);
      __builtin_amdgcn_s_setprio(0);
    }
    VMWAIT(0);
    __builtin_amdgcn_s_barrier();
  }
#undef STAGE_G1

#pragma unroll
  for (int m = 0; m < MF; ++m) {
    int row0 = bi * BM + wr2 * 32 + m * 16 + 4 * l16;
#pragma unroll
    for (int n = 0; n < NF; ++n) {
      int col = bj * BN + wc2 * 32 + n * 16 + l15;
#pragma unroll
      for (int r = 0; r < 4; ++r)
        Cb[(size_t)(row0 + r) * DDIM + col] = f2bf(acc[m][n][r]);
    }
  }
}

// ---------- GEMM2: R5 champion loop, persistent double-tile over N ----------
// Block computes (bi, 2bjp) then (bi, 2bjp+1): tile-1 prologue stage hides
// under epilogue-0; A-panel fetched once per pair. Mask prefetch in epilogue.
__launch_bounds__(512, 4)
__global__ void gemm2_k(const unsigned short* __restrict__ A,
                        const unsigned short* __restrict__ B,
                        const float* __restrict__ linl,
                        const float* __restrict__ linr,
                        const void* __restrict__ mask,
                        const int* __restrict__ mflag,
                        float* __restrict__ scores,
                        float* __restrict__ xout) {
  constexpr int K = DDIM;
  __shared__ __align__(16) unsigned short sAB[2][2][128][64];  // [buf][A/B] 64 KB

  // XCD patches: 16 patches of 8(bi) x 4(bjp); 2 patches per XCD; 4 MB L2 footprint
  const int lin = blockIdx.x;             // grid 512
  const int xcd = lin & 7, s = lin >> 3;  // s: 0..63
  const int pid = xcd * 2 + (s >> 5);     // 0..15
  const int w = s & 31;
  const int bi = (pid >> 2) * 8 + (w >> 2);   // 0..31
  const int bjp = (pid & 3) * 4 + (w & 3);    // 0..15
  const int bj0 = bjp * 2, bj1 = bjp * 2 + 1;

  const int tid = threadIdx.x;
  const int wid = tid >> 6, lane = tid & 63;
  const int wr2 = wid >> 2, wc2 = wid & 3;  // 2(M) x 4(N), wave 64x32
  const int l15 = lane & 15, l16 = lane >> 4;
  const int xm = lane & 7;

  const int srow0 = tid >> 3;
  const int swslot = (tid & 7) ^ (srow0 & 7);
  const unsigned short* Ag = A + (size_t)(bi * 128 + srow0) * K + swslot * 8;
  const unsigned short* Bg0 = B + (size_t)(bj0 * 128 + srow0) * K + swslot * 8;
  const unsigned short* Bg1 = Bg0 + (size_t)128 * K;

  const int mf = *mflag;
  f32x4 acc[4][2];

#define STG(BUF, BG, K0)                                                     \
  {                                                                          \
    _Pragma("unroll") for (int j = 0; j < 2; ++j) {                          \
      gload_lds16(Ag + (size_t)(j * 64) * K + (K0),                          \
                  (unsigned short*)&sAB[BUF][0][0][0] + j * 4096 + wid * 512);\
      gload_lds16((BG) + (size_t)(j * 64) * K + (K0),                        \
                  (unsigned short*)&sAB[BUF][1][0][0] + j * 4096 + wid * 512);\
    }                                                                        \
  }

#define KLOOP(BG)                                                            \
  for (int t = 0; t < 16; ++t) {                                             \
    const int cur = t & 1, nxt = cur ^ 1;                                    \
    if (t < 15) STG(nxt, BG, (t + 1) * 64)                                   \
    _Pragma("unroll") for (int kk = 0; kk < 2; ++kk) {                       \
      s16x8 Areg[4], Breg[2];                                                \
      _Pragma("unroll") for (int m = 0; m < 4; ++m)                          \
          Areg[m] = *(const s16x8*)&((unsigned short*)&sAB[cur][0][0][0])    \
              [(wr2 * 64 + m * 16 + l15) * 64 + ((((kk << 2) | l16) ^ xm) << 3)]; \
      _Pragma("unroll") for (int n = 0; n < 2; ++n)                          \
          Breg[n] = *(const s16x8*)&((unsigned short*)&sAB[cur][1][0][0])    \
              [(wc2 * 32 + n * 16 + l15) * 64 + ((((kk << 2) | l16) ^ xm) << 3)]; \
      __builtin_amdgcn_s_setprio(1);                                         \
      _Pragma("unroll") for (int m = 0; m < 4; ++m)                          \
          _Pragma("unroll") for (int n = 0; n < 2; ++n)                      \
              acc[m][n] = __builtin_amdgcn_mfma_f32_16x16x32_bf16(           \
                  Areg[m], Breg[n], acc[m][n], 0, 0, 0);                     \
      __builtin_amdgcn_s_setprio(0);                                         \
    }                                                                        \
    if (t < 15) { VMWAIT(0); __builtin_amdgcn_s_barrier(); }                 \
  }

  // epilogue: 2 half-passes; CFBUF = LDS buf used as f32[64][128] scratch;
  // mask prefetched before the repack barriers so HBM latency hides under LDS.
#define EPILOG(CFBUF, BJ)                                                    \
  {                                                                          \
    float* Cf = (float*)&sAB[CFBUF][0][0][0];                                \
    _Pragma("unroll") for (int h = 0; h < 2; ++h) {                          \
      unsigned pmb[4]; i32x4 pmi[4];                                         \
      _Pragma("unroll") for (int it = 0; it < 4; ++it) {                     \
        int fid = it * 512 + tid;                                            \
        int plr = fid >> 5, pc0 = (fid & 31) << 2;                           \
        size_t pidx = (size_t)(bi * 128 + h * 64 + plr) * NTOK +             \
                      (BJ)*128 + pc0;                                        \
        if (mf) pmb[it] = *(const unsigned*)((const unsigned char*)mask + pidx); \
        else pmi[it] = *(const i32x4*)((const int*)mask + pidx);             \
      }                                                                      \
      __syncthreads();                                                       \
      if (wr2 == h) {                                                        \
        _Pragma("unroll") for (int m = 0; m < 4; ++m) {                      \
          _Pragma("unroll") for (int n = 0; n < 2; ++n) {                    \
            int lc = wc2 * 32 + n * 16 + l15;                                \
            _Pragma("unroll") for (int r = 0; r < 4; ++r) {                  \
              int lr = m * 16 + l16 * 4 + r;                                 \
              Cf[lr * 128 + (lc ^ (((lr >> 2) & 1) << 4))] = acc[m][n][r];   \
            }                                                                \
          }                                                                  \
        }                                                                    \
      }                                                                      \
      __syncthreads();                                                       \
      _Pragma("unroll") for (int it = 0; it < 4; ++it) {                     \
        int fid = it * 512 + tid;                                            \
        int lr = fid >> 5, sl = fid & 31;                                    \
        int c0 = sl << 2;                                                    \
        int cs = c0 ^ (((lr >> 2) & 1) << 4);                                \
        f32x4 v4 = *(const f32x4*)&Cf[lr * 128 + cs];                        \
        int row = bi * 128 + h * 64 + lr;                                    \
        int colb = (BJ)*128 + c0;                                            \
        float ll = linl[row];                                                \
        f32x4 rr = *(const f32x4*)&linr[colb];                               \
        size_t idx = (size_t)row * NTOK + colb;                              \
        f32x4 o, sc;                                                         \
        if (mf) {                                                            \
          _Pragma("unroll") for (int e = 0; e < 4; ++e) {                    \
            float v = v4[e] + ll + rr[e];                                    \
            v = v > 0.f ? v : 0.f;                                           \
            o[e] = v; sc[e] = ((pmb[it] >> (8 * e)) & 255u) ? v : 0.f;       \
          }                                                                  \
        } else {                                                             \
          _Pragma("unroll") for (int e = 0; e < 4; ++e) {                    \
            float v = v4[e] + ll + rr[e];                                    \
            v = v > 0.f ? v : 0.f;                                           \
            o[e] = v; sc[e] = pmi[it][e] ? v : 0.f;                          \
          }                                                                  \
        }                                                                    \
        *(f32x4*)&xout[idx] = o;                                             \
        *(f32x4*)&scores[idx] = sc;                                          \
      }                                                                      \
    }                                                                        \
  }

  // ---- tile 0 ----
#pragma unroll
  for (int m = 0; m < 4; ++m)
#pragma unroll
    for (int n = 0; n < 2; ++n) acc[m][n] = (f32x4){0.f, 0.f, 0.f, 0.f};
  STG(0, Bg0, 0)
  VMWAIT(0);
  __builtin_amdgcn_s_barrier();
  KLOOP(Bg0)

  // stage tile-1 k0 into buf0 (its last reader barrier'd at t=14);
  // the loads fly under epilogue-0 (repack scratch = buf1).
  STG(0, Bg1, 0)
  EPILOG(1, bj0)

  // ---- tile 1 ----
  VMWAIT(0);
  __builtin_amdgcn_s_barrier();
#pragma unroll
  for (int m = 0; m < 4; ++m)
#pragma unroll
    for (int n = 0; n < 2; ++n) acc[m][n] = (f32x4){0.f, 0.f, 0.f, 0.f};
  KLOOP(Bg1)
  EPILOG(0, bj1)

#undef STG
#undef KLOOP
#undef EPILOG
}

extern "C" void kernel_launch(void* const* d_in, const int* in_sizes, int n_in,
                              void* d_out, int out_size, void* d_ws, size_t ws_size,
                              hipStream_t stream) {
  const float* x_l    = (const float*)d_in[0];
  const float* x_r    = (const float*)d_in[1];
  const void*  maskp  = (const void*)d_in[2];
  const float* matrix = (const float*)d_in[3];
  const float* bias   = (const float*)d_in[4];
  const float* wl     = (const float*)d_in[5];
  const float* bl     = (const float*)d_in[6];
  const float* wr     = (const float*)d_in[7];
  const float* br     = (const float*)d_in[8];

  unsigned short* XLb = (unsigned short*)d_ws;
  unsigned short* XRb = XLb + (size_t)NTOK * DDIM;
  unsigned short* XMb = XRb + (size_t)NTOK * DDIM;
  unsigned short* Mtb = XMb + (size_t)NTOK * DDIM;
  float* lin_l = (float*)(Mtb + (size_t)DDIM * DDIM);
  float* lin_r = lin_l + NTOK;
  int* mflag = (int*)(lin_r + NTOK);

  float* scores = (float*)d_out;
  float* xout = scores + (size_t)NTOK * NTOK;

  convlin2_k<<<2048, 256, 0, stream>>>(x_l, x_r, wl, wr, bl, br, bias,
                                       XLb, XRb, lin_l, lin_r);
  transpose_bf16_k<<<dim3(32, 32), dim3(32, 8), 0, stream>>>(matrix, Mtb);
  detect_mask_k<<<1, 256, 0, stream>>>((const unsigned char*)maskp, mflag);

  // GEMM1: XM = x_l @ M (64x128 tile, grid 512)
  gemm1_k<<<512, 512, 0, stream>>>(XLb, Mtb, XMb);

  // GEMM2: x = relu(XM @ XR^T + lin), scores = mask?x:0 (persistent N-pairs)
  gemm2_k<<<512, 512, 0, stream>>>(XMb, XRb, lin_l, lin_r, maskp, mflag,
                                   scores, xout);
}

// Round 13
// 102.412 us; speedup vs baseline: 1.2579x; 1.2579x over previous
//
#include <hip/hip_runtime.h>
#include <stdint.h>
#include <stddef.h>

#define NTOK 4096
#define DDIM 1024

typedef __attribute__((ext_vector_type(4))) float f32x4;
typedef __attribute__((ext_vector_type(8))) short s16x8;
typedef __attribute__((ext_vector_type(4))) unsigned short u16x4;

__device__ __forceinline__ unsigned short f2bf(float f) {
  union { float f; unsigned u; } v; v.f = f;
  unsigned u = v.u + 0x7fffu + ((v.u >> 16) & 1u);
  return (unsigned short)(u >> 16);
}

__device__ __forceinline__ void gload_lds16(const void* g, void* l) {
  __builtin_amdgcn_global_load_lds(
      (const __attribute__((address_space(1))) void*)g,
      (__attribute__((address_space(3))) void*)l, 16, 0, 0);
}

// ---------- fused fp32->bf16 convert + lin dot, both inputs in one launch ----------
__global__ void convlin2_k(const float* __restrict__ xl, const float* __restrict__ xr,
                           const float* __restrict__ wl, const float* __restrict__ wr,
                           const float* __restrict__ bl, const float* __restrict__ br,
                           const float* __restrict__ bias,
                           unsigned short* __restrict__ xlb, unsigned short* __restrict__ xrb,
                           float* __restrict__ linl, float* __restrict__ linr) {
  const int isR = blockIdx.x >> 10;
  const float* x = isR ? xr : xl;
  const float* w = isR ? wr : wl;
  const float badd = isR ? br[0] : (bl[0] + bias[0]);
  unsigned short* xb = isR ? xrb : xlb;
  float* lin = isR ? linr : linl;

  int wv = threadIdx.x >> 6, lane = threadIdx.x & 63;
  int row = ((blockIdx.x & 1023) << 2) + wv;
  const f32x4* xrow = (const f32x4*)(x + (size_t)row * DDIM);
  const f32x4* w4 = (const f32x4*)w;
  u16x4* xb4 = (u16x4*)(xb + (size_t)row * DDIM);
  float s = 0.f;
  for (int j = lane; j < DDIM / 4; j += 64) {
    f32x4 a = xrow[j], c = w4[j];
    s += a[0] * c[0] + a[1] * c[1] + a[2] * c[2] + a[3] * c[3];
    u16x4 o;
    o[0] = f2bf(a[0]); o[1] = f2bf(a[1]); o[2] = f2bf(a[2]); o[3] = f2bf(a[3]);
    xb4[j] = o;
  }
#pragma unroll
  for (int off = 32; off; off >>= 1) s += __shfl_down(s, off);
  if (lane == 0) lin[row] = s + badd;
}

// ---------- transpose-convert M fp32 -> Mt bf16 ----------
__global__ void transpose_bf16_k(const float* __restrict__ M,
                                 unsigned short* __restrict__ Mt) {
  __shared__ unsigned short tile[32][33];
  int tx = threadIdx.x, ty = threadIdx.y;
  int bx = blockIdx.x, by = blockIdx.y;
  int x = bx * 32 + tx;
  for (int i = ty; i < 32; i += 8)
    tile[i][tx] = f2bf(M[(size_t)(by * 32 + i) * DDIM + x]);
  __syncthreads();
  int ox = by * 32 + tx;
  for (int i = ty; i < 32; i += 8)
    Mt[(size_t)(bx * 32 + i) * DDIM + ox] = tile[tx][i];
}

// ---------- detect mask element width ----------
__global__ void detect_mask_k(const unsigned char* __restrict__ m, int* __restrict__ flag) {
  __shared__ int f;
  if (threadIdx.x == 0) f = 0;
  __syncthreads();
  int any = 0;
  for (int i = threadIdx.x; i < 4096; i += 256)
    if ((i & 3) && m[i]) any = 1;
  if (any) atomicOr(&f, 1);
  __syncthreads();
  if (threadIdx.x == 0) *flag = f;  // 1 => byte mask, 0 => int32 mask
}

// ---------- double-buffered BT GEMM (R5 champion, verbatim) ----------
// C[BM x BN] per block; A[M][K] * B[N][K]^T, bf16 in, fp32 acc.
// 8 waves as 2(M) x 4(N); T2 both-sides swizzle; coalesced f32x4 epilogue.

template <int EPI, int BM, int BN, int NBJ>
__launch_bounds__(512, 4)
__global__ void gemm_db_k(const unsigned short* __restrict__ A,
                          const unsigned short* __restrict__ B,
                          int K, int ldc,
                          unsigned short* __restrict__ Cb,
                          const float* __restrict__ linl,
                          const float* __restrict__ linr,
                          const void* __restrict__ mask,
                          const int* __restrict__ mflag,
                          float* __restrict__ scores,
                          float* __restrict__ xout) {
  constexpr int MF = BM / 32;
  constexpr int NF = BN / 64;
  constexpr int AI = BM / 64;
  constexpr int BI = BN / 64;
  constexpr int SMEMB = (2 * BM * 64 + 2 * BN * 64) * 2;  // == BM*BN*4 at 128x128
  __shared__ __align__(16) unsigned char smem[SMEMB];
  unsigned short* Asb = (unsigned short*)smem;
  unsigned short* Bsb = Asb + 2 * BM * 64;

  const int lin = blockIdx.x;
  int bi, bj;
  if constexpr (EPI == 1) {
    // patch swizzle: 32 patches of 4(bi) x 8(bj) blocks -> 3MB L2 footprint
    const int xcd = lin & 7, s = lin >> 3;
    const int p = (s >> 5) * 8 + xcd;  // 0..31
    const int w = s & 31;
    bi = (p >> 2) * 4 + (w >> 3);
    bj = (p & 3) * 8 + (w & 7);
  } else {
    const int cpx = gridDim.x >> 3;
    const int swz = (lin & 7) * cpx + (lin >> 3);
    bi = swz / NBJ; bj = swz % NBJ;
  }

  const int tid = threadIdx.x;
  const int wid = tid >> 6, lane = tid & 63;
  const int wr2 = wid >> 2, wc2 = wid & 3;
  const int l15 = lane & 15, l16 = lane >> 4;
  const int xm = lane & 7;

  const int srow0 = tid >> 3;
  const int swslot = (tid & 7) ^ (srow0 & 7);
  const unsigned short* Ag = A + (size_t)(bi * BM + srow0) * K + swslot * 8;
  const unsigned short* Bg = B + (size_t)(bj * BN + srow0) * K + swslot * 8;

  f32x4 acc[MF][NF] = {};

#define STAGE_T(BUF, K0)                                                     \
  {                                                                          \
    _Pragma("unroll") for (int j = 0; j < AI; ++j)                           \
        gload_lds16(Ag + (size_t)(j * 64) * K + (K0),                        \
                    Asb + (BUF)*BM * 64 + j * 4096 + wid * 512);             \
    _Pragma("unroll") for (int j = 0; j < BI; ++j)                           \
        gload_lds16(Bg + (size_t)(j * 64) * K + (K0),                        \
                    Bsb + (BUF)*BN * 64 + j * 4096 + wid * 512);             \
  }

  STAGE_T(0, 0)
  asm volatile("s_waitcnt vmcnt(0)" ::: "memory");
  __builtin_amdgcn_s_barrier();

  const int nt = K >> 6;
  for (int t = 0; t < nt; ++t) {
    const int cur = t & 1, nxt = cur ^ 1;
    if (t + 1 < nt) STAGE_T(nxt, (t + 1) * 64)
#pragma unroll
    for (int kk = 0; kk < 2; ++kk) {
      s16x8 Areg[MF], Breg[NF];
#pragma unroll
      for (int m = 0; m < MF; ++m)
        Areg[m] = *(const s16x8*)(Asb + cur * BM * 64 +
                                  (wr2 * (BM / 2) + m * 16 + l15) * 64 +
                                  ((((kk << 2) | l16) ^ xm) << 3));
#pragma unroll
      for (int n = 0; n < NF; ++n)
        Breg[n] = *(const s16x8*)(Bsb + cur * BN * 64 +
                                  (wc2 * (BN / 4) + n * 16 + l15) * 64 +
                                  ((((kk << 2) | l16) ^ xm) << 3));
      __builtin_amdgcn_s_setprio(1);
#pragma unroll
      for (int m = 0; m < MF; ++m)
#pragma unroll
        for (int n = 0; n < NF; ++n)
          acc[m][n] = __builtin_amdgcn_mfma_f32_16x16x32_bf16(
              Areg[m], Breg[n], acc[m][n], 0, 0, 0);
      __builtin_amdgcn_s_setprio(0);
    }
    asm volatile("s_waitcnt vmcnt(0)" ::: "memory");
    __builtin_amdgcn_s_barrier();
  }
#undef STAGE_T

  if constexpr (EPI == 0) {
    // bf16 C write (small output, GEMM1)
#pragma unroll
    for (int m = 0; m < MF; ++m) {
      int row0 = bi * BM + wr2 * (BM / 2) + m * 16 + 4 * l16;
#pragma unroll
      for (int n = 0; n < NF; ++n) {
        int col = bj * BN + wc2 * (BN / 4) + n * 16 + l15;
#pragma unroll
        for (int r = 0; r < 4; ++r)
          Cb[(size_t)(row0 + r) * ldc + col] = f2bf(acc[m][n][r]);
      }
    }
  } else {
    // coalesced epilogue: acc -> LDS (f32 128x128) -> f32x4 streaming stores
    __syncthreads();
    float* Cf = (float*)smem;
#pragma unroll
    for (int m = 0; m < MF; ++m) {
      int lr0 = wr2 * 64 + m * 16 + l16 * 4;
#pragma unroll
      for (int n = 0; n < NF; ++n) {
        int lc = wc2 * 32 + n * 16 + l15;
#pragma unroll
        for (int r = 0; r < 4; ++r)
          Cf[(lr0 + r) * 128 + lc] = acc[m][n][r];
      }
    }
    __syncthreads();
    const int mf = *mflag;
    const int r0 = tid >> 5, c0 = (tid & 31) << 2;
#pragma unroll
    for (int p = 0; p < 8; ++p) {
      int lr = p * 16 + r0;
      int row = bi * BM + lr;
      int colb = bj * BN + c0;
      f32x4 v4 = *(const f32x4*)&Cf[lr * 128 + c0];
      f32x4 rr = *(const f32x4*)&linr[colb];
      float ll = linl[row];
      size_t idx = (size_t)row * NTOK + colb;
      f32x4 o, sc;
      if (mf) {
        const unsigned char* mp = (const unsigned char*)mask + idx;
#pragma unroll
        for (int e = 0; e < 4; ++e) {
          float v = v4[e] + ll + rr[e];
          v = v > 0.f ? v : 0.f;
          o[e] = v; sc[e] = mp[e] ? v : 0.f;
        }
      } else {
        const int* mp = (const int*)mask + idx;
#pragma unroll
        for (int e = 0; e < 4; ++e) {
          float v = v4[e] + ll + rr[e];
          v = v > 0.f ? v : 0.f;
          o[e] = v; sc[e] = mp[e] ? v : 0.f;
        }
      }
      *(f32x4*)&xout[idx] = o;
      *(f32x4*)&scores[idx] = sc;
    }
  }
}

extern "C" void kernel_launch(void* const* d_in, const int* in_sizes, int n_in,
                              void* d_out, int out_size, void* d_ws, size_t ws_size,
                              hipStream_t stream) {
  const float* x_l    = (const float*)d_in[0];
  const float* x_r    = (const float*)d_in[1];
  const void*  maskp  = (const void*)d_in[2];
  const float* matrix = (const float*)d_in[3];
  const float* bias   = (const float*)d_in[4];
  const float* wl     = (const float*)d_in[5];
  const float* bl     = (const float*)d_in[6];
  const float* wr     = (const float*)d_in[7];
  const float* br     = (const float*)d_in[8];

  unsigned short* XLb = (unsigned short*)d_ws;
  unsigned short* XRb = XLb + (size_t)NTOK * DDIM;
  unsigned short* XMb = XRb + (size_t)NTOK * DDIM;
  unsigned short* Mtb = XMb + (size_t)NTOK * DDIM;
  float* lin_l = (float*)(Mtb + (size_t)DDIM * DDIM);
  float* lin_r = lin_l + NTOK;
  int* mflag = (int*)(lin_r + NTOK);

  float* scores = (float*)d_out;
  float* xout = scores + (size_t)NTOK * NTOK;

  convlin2_k<<<2048, 256, 0, stream>>>(x_l, x_r, wl, wr, bl, br, bias,
                                       XLb, XRb, lin_l, lin_r);
  transpose_bf16_k<<<dim3(32, 32), dim3(32, 8), 0, stream>>>(matrix, Mtb);
  detect_mask_k<<<1, 256, 0, stream>>>((const unsigned char*)maskp, mflag);

  // GEMM1: XM = x_l @ M   (64x128 tile, grid 512 -> 2-3 blocks/CU)
  gemm_db_k<0, 64, 128, 8><<<512, 512, 0, stream>>>(
      XLb, Mtb, DDIM, DDIM, XMb,
      nullptr, nullptr, nullptr, nullptr, nullptr, nullptr);

  // GEMM2 + epilogue (128x128 tile, grid 1024 -> 2 blocks/CU)
  gemm_db_k<1, 128, 128, 32><<<1024, 512, 0, stream>>>(
      XMb, XRb, DDIM, NTOK, nullptr,
      lin_l, lin_r, maskp, mflag, scores, xout);
}